// Round 18
// baseline (191.989 us; speedup 1.0000x reference)
//
#include <hip/hip_runtime.h>
#include <stdint.h>

// 3-layer GCN, gather-only aggregation off a per-node CSR.
// R33 = R32 (best, 187.4us) + ONE isolated change: k_agg30_l2 processes
// FOUR 32-node tiles per block (grid 6250 -> 1563). Per-block fixed cost --
// W2s staging (1024 floats + barrier), W3/b2 staging, dispatch ramp -- was
// paid per 32 nodes; now amortized 4x. Per tile: {register gather/compute ->
// barrier (hsh reuse guard) -> hsh write -> barrier -> all-lane phase 2}.
// Same 256-thr blocks / 8.7KB LDS -> occupancy preserved; per-node
// accumulation order unchanged -> absmax unchanged.
//  k_bin: CHUNK 6400, single-pass (edges packed in registers), pairs loads.
//  k_bucket_ptr: count + scan -> iptr2, dinv, p1.
//  k_csr_agg: LDS stage + coalesced csr copy-out + per-node dim-2 agg -> t4.
//  k_agg30_l2: fused RECOMPUTE aggregation + layer-2 matmul, all-lane
//  phase 2, 4 tiles/block.
//  k_agg1: 8-lane-group gather (R32, -3.5us), shfl_xor reduce.
// Packed edge = (src<<9)|(dst&511), src < 2^18.

#define CAP 9216    // bucket region capacity; mean 8184, sigma 90 -> +11 sigma
#define CHUNK 6400  // edges per k_bin block

__device__ __forceinline__ unsigned short f2bf(float f) {  // RNE, no NaN inputs
    unsigned u = __float_as_uint(f);
    unsigned r = ((u >> 16) & 1u) + 0x7FFFu;
    return (unsigned short)((u + r) >> 16);
}
__device__ __forceinline__ float bf2f(unsigned short h) {
    return __uint_as_float((unsigned)h << 16);
}

// Per-block int64-vs-int32 detect: int64 edge values < 2^18 => all high
// words zero; int32 data at those offsets is src values, ~surely nonzero.
__device__ __forceinline__ int detect64(const unsigned* ei, int* s_nz, int t) {
    unsigned v = ei[2 * (t & 255) + 1];
    if (v != 0) atomicAdd(s_nz, 1);
    __syncthreads();
    return (*s_nz == 0);
}

// Fused binning with local counting sort and coalesced copy-out. 512 thr.
// Edge list read ONCE (pairs via vector loads); packed edges + bucket ids
// held in statically-indexed registers across the scan.
__global__ __launch_bounds__(512) void k_bin(const void* ei, long long E,
                                             int* gcnt, unsigned* binned, int B) {
    __shared__ int cursor[512];
    __shared__ int delta[512];
    __shared__ int wsum[8];
    __shared__ int s_total;
    __shared__ unsigned sv[CHUNK];
    __shared__ unsigned short sb[CHUNK];
    __shared__ int s_nz;
    int t = threadIdx.x, blk = blockIdx.x;
    if (t == 0) s_nz = 0;
    cursor[t] = 0;
    __syncthreads();
    int f = detect64((const unsigned*)ei, &s_nz, t);
    long long s = (long long)blk * CHUNK, e = min(E, s + CHUNK);
    // ---- single global read: pack edges into register slots ----
    unsigned pv[14];
    unsigned short pbk[14];
    if (f) {
        const long long* p = (const long long*)ei;
#pragma unroll
        for (int k = 0; k < 7; k++) {
            long long i = s + 2 * t + (long long)k * 1024;
            if (i + 1 < e) {
                longlong2 sp = *(const longlong2*)(p + i);
                longlong2 dp = *(const longlong2*)(p + E + i);
                pv[2 * k] = ((unsigned)(int)sp.x << 9) | (unsigned)((int)dp.x & 511);
                pbk[2 * k] = (unsigned short)(((int)dp.x) >> 9);
                pv[2 * k + 1] = ((unsigned)(int)sp.y << 9) | (unsigned)((int)dp.y & 511);
                pbk[2 * k + 1] = (unsigned short)(((int)dp.y) >> 9);
            } else if (i < e) {
                int sval = (int)p[i], dv = (int)p[E + i];
                pv[2 * k] = ((unsigned)sval << 9) | (unsigned)(dv & 511);
                pbk[2 * k] = (unsigned short)(dv >> 9);
            }
        }
    } else {
        const int* p = (const int*)ei;
#pragma unroll
        for (int k = 0; k < 7; k++) {
            long long i = s + 2 * t + (long long)k * 1024;
            if (i + 1 < e) {
                int2 sp = *(const int2*)(p + i);
                int2 dp = *(const int2*)(p + E + i);
                pv[2 * k] = ((unsigned)sp.x << 9) | (unsigned)(dp.x & 511);
                pbk[2 * k] = (unsigned short)(dp.x >> 9);
                pv[2 * k + 1] = ((unsigned)sp.y << 9) | (unsigned)(dp.y & 511);
                pbk[2 * k + 1] = (unsigned short)(dp.y >> 9);
            } else if (i < e) {
                int sval = p[i], dv = p[E + i];
                pv[2 * k] = ((unsigned)sval << 9) | (unsigned)(dv & 511);
                pbk[2 * k] = (unsigned short)(dv >> 9);
            }
        }
    }
    // ---- histogram from registers ----
#pragma unroll
    for (int k = 0; k < 14; k++) {
        long long i = s + 2 * t + (long long)(k >> 1) * 1024 + (k & 1);
        if (i < e) atomicAdd(&cursor[pbk[k]], 1);
    }
    __syncthreads();
    // exclusive scan over 512 counts: wave shuffle scan + cross-wave offsets
    int c = cursor[t];
    int lane = t & 63, wid = t >> 6;
    int inc = c;
#pragma unroll
    for (int off = 1; off < 64; off <<= 1) {
        int up = __shfl_up(inc, off, 64);
        if (lane >= off) inc += up;
    }
    if (lane == 63) wsum[wid] = inc;
    __syncthreads();
    int base = 0;
    for (int k = 0; k < wid; k++) base += wsum[k];
    int ex = base + inc - c;
    if (t == 511) s_total = ex + c;
    int claim = c ? atomicAdd(&gcnt[t], c) : 0;
    delta[t] = t * CAP + claim - ex;
    cursor[t] = ex;
    __syncthreads();
    // ---- scatter into LDS from registers ----
#pragma unroll
    for (int k = 0; k < 14; k++) {
        long long i = s + 2 * t + (long long)(k >> 1) * 1024 + (k & 1);
        if (i < e) {
            int pos = atomicAdd(&cursor[pbk[k]], 1);
            sv[pos] = pv[k];
            sb[pos] = pbk[k];
        }
    }
    __syncthreads();
    // linear copy-out (consecutive threads -> consecutive addresses)
    int total = s_total;
    for (int i = t; i < total; i += 512)
        binned[delta[sb[i]] + i] = sv[i];
}

// Per-bucket count + scan only: iptr2, dinv, p1 = x*dinv. 1024 threads.
// (Scatter moved to k_csr_agg, which needs p1 globally complete.)
__global__ __launch_bounds__(1024) void k_bucket_ptr(
        const unsigned* binned, const int* gcnt, const float* x, int2* iptr2,
        float* dinv, float2* p1, int n) {
    __shared__ int cur[512];
    __shared__ int wsum[16];
    int t = threadIdx.x, b = blockIdx.x;
    if (t < 512) cur[t] = 0;
    __syncthreads();
    int cnt = gcnt[b];
    const unsigned* bp = binned + (size_t)b * CAP;
    for (int i = t; i < cnt; i += 1024)
        atomicAdd(&cur[bp[i] & 511u], 1);
    __syncthreads();
    int c = (t < 512) ? cur[t] : 0;
    int lane = t & 63, wid = t >> 6;
    int inc = c;
#pragma unroll
    for (int off = 1; off < 64; off <<= 1) {
        int up = __shfl_up(inc, off, 64);
        if (lane >= off) inc += up;
    }
    if (lane == 63) wsum[wid] = inc;
    __syncthreads();
    int base = 0;
    for (int k = 0; k < wid; k++) base += wsum[k];
    int ex = base + inc - c;
    int gbase = b * CAP;
    if (t < 512) {
        int node = b * 512 + t;
        if (node < n) {
            iptr2[node] = make_int2(gbase + ex, gbase + ex + c);
            float dg = (float)(c + 1);  // +1 self loop
            float r = rsqrtf(dg);
            r = r * (1.5f - 0.5f * dg * r * r);  // Newton refine
            dinv[node] = r;
            p1[node] = make_float2(x[2 * node] * r, x[2 * node + 1] * r);
        }
    }
}

// Phase A: scatter src ids into LDS stage (cursors seeded from iptr2),
// linear coalesced copy-out to csr. Phase B: threads t<512 walk their own
// node's staged segment, gather p1[src] (independent pipelined loads, no
// value atomics), finalize t4 = ((p1_self+agg)*r, r).
__global__ __launch_bounds__(1024) void k_csr_agg(
        const unsigned* binned, const int* gcnt, const int2* iptr2,
        const float* dinv, const float2* p1, int* csr, float4* t4, int n) {
    __shared__ int cur[512];
    __shared__ int stage[CAP];
    int t = threadIdx.x, b = blockIdx.x;
    int seg0 = 0, node = b * 512 + t;
    if (t < 512) {
        seg0 = (node < n) ? iptr2[node].x - b * CAP : 0;
        cur[t] = seg0;
    }
    __syncthreads();
    int cnt = gcnt[b];
    const unsigned* bp = binned + (size_t)b * CAP;
    for (int i = t; i < cnt; i += 1024) {
        unsigned p = bp[i];
        int pos = atomicAdd(&cur[p & 511u], 1);
        stage[pos] = (int)(p >> 9);
    }
    __syncthreads();
    // linear coalesced copy-out
    int gbase = b * CAP;
    for (int i = t; i < cnt; i += 1024)
        csr[gbase + i] = stage[i];
    // phase B: per-node dim-2 aggregation off the staged segment
    if (t < 512 && node < n) {
        int e0 = cur[t];  // segment end after scatter
        float ax = 0.f, ay = 0.f;
        int i = seg0;
        for (; i + 3 < e0; i += 4) {
            int u0 = stage[i], u1 = stage[i + 1];
            int u2 = stage[i + 2], u3 = stage[i + 3];
            float2 q0 = p1[u0], q1 = p1[u1], q2 = p1[u2], q3 = p1[u3];
            ax += (q0.x + q1.x) + (q2.x + q3.x);
            ay += (q0.y + q1.y) + (q2.y + q3.y);
        }
        for (; i < e0; i++) {
            float2 q = p1[stage[i]];
            ax += q.x; ay += q.y;
        }
        float r = dinv[node];
        float2 sp = p1[node];  // self loop
        t4[node] = make_float4((sp.x + ax) * r, (sp.y + ay) * r, r, 0.f);
    }
}

// FUSED dim-30 aggregation + layer 2 (all-lane phase 2), 4 TILES/BLOCK.
// Weights staged once per block; per tile: register gather/compute ->
// barrier (hsh reuse guard) -> hsh write -> barrier -> phase 2.
__global__ void k_agg30_l2(const float4* t4, const int2* iptr2, const int* csr,
                           const float* W1, const float* b1, const float* x,
                           const float* W2, const float* W3, const float* b2,
                           float* p3, int n) {
    __shared__ float hsh[32 * 33];   // fp32 h rows, stride 33 (conflict-free)
    __shared__ float W2s[32 * 32];   // padded rows (j=30,31 -> 0)
    __shared__ float W3s[32];
    __shared__ float b2s[32];
    int t = threadIdx.x;
    for (int i = t; i < 1024; i += 256) {
        int k = i >> 5, j = i & 31;
        W2s[i] = (j < 30) ? W2[k * 30 + j] : 0.f;
    }
    if (t < 32) {
        W3s[t] = W3[t];
        b2s[t] = (t < 30) ? b2[t] : 0.f;
    }

    int grp = t >> 3, l = t & 7;
    float w0[4], w1[4], bb[4];
#pragma unroll
    for (int k = 0; k < 4; k++) {
        int j = 4 * l + k;
        bool ok = (j < 30);
        w0[k] = ok ? W1[j] : 0.f;
        w1[k] = ok ? W1[30 + j] : 0.f;
        bb[k] = ok ? b1[j] : 0.f;
    }

    for (int tt = 0; tt < 4; tt++) {
        int g = (blockIdx.x * 4 + tt) * 32 + grp;
        bool active = (g < n);
        float4 qs = active ? t4[g] : make_float4(0.f, 0.f, 0.f, 0.f);
        float2 xg = active ? *(const float2*)(x + 2 * g) : make_float2(0.f, 0.f);
        float a0 = fmaxf(fmaf(qs.x, w0[0], fmaf(qs.y, w1[0], bb[0])), 0.f) * qs.z;
        float a1 = fmaxf(fmaf(qs.x, w0[1], fmaf(qs.y, w1[1], bb[1])), 0.f) * qs.z;
        float a2 = fmaxf(fmaf(qs.x, w0[2], fmaf(qs.y, w1[2], bb[2])), 0.f) * qs.z;
        float a3 = fmaxf(fmaf(qs.x, w0[3], fmaf(qs.y, w1[3], bb[3])), 0.f) * qs.z;
        int2 se = active ? iptr2[g] : make_int2(0, 0);
        int s = se.x, e = se.y;
        for (int i = s; i < e; i += 8) {
            int m = e - i;  // valid edges in this chunk (>0)
            int u = (l < m) ? csr[i + l] : 0;
            float4 q = t4[u];
            if (l >= m) { q.x = 0.f; q.y = 0.f; q.z = 0.f; }
#pragma unroll
            for (int k = 0; k < 8; k++) {
                float bx = __shfl(q.x, k, 8);
                float by = __shfl(q.y, k, 8);
                float br = __shfl(q.z, k, 8);
                a0 = fmaf(fmaxf(fmaf(bx, w0[0], fmaf(by, w1[0], bb[0])), 0.f), br, a0);
                a1 = fmaf(fmaxf(fmaf(bx, w0[1], fmaf(by, w1[1], bb[1])), 0.f), br, a1);
                a2 = fmaf(fmaxf(fmaf(bx, w0[2], fmaf(by, w1[2], bb[2])), 0.f), br, a2);
                a3 = fmaf(fmaxf(fmaf(bx, w0[3], fmaf(by, w1[3], bb[3])), 0.f), br, a3);
            }
        }
        // guard: previous tile's phase 2 must be done reading hsh
        // (first iteration: doubles as the weight-staging barrier)
        __syncthreads();
        if (active) {
            float r = qs.z;
            int hb = grp * 33 + 4 * l;  // 2-way bank alias = free
            hsh[hb + 0] = a0 * r;
            hsh[hb + 1] = a1 * r;
            hsh[hb + 2] = a2 * r;
            hsh[hb + 3] = a3 * r;
        }
        __syncthreads();
        // ---- phase 2: all lanes; lane l owns output dims j=4l..4l+3 ----
        if (active) {
            int j0 = 4 * l;
            float ax = qs.x, ay = qs.y, rr = qs.z;
            float c0 = fmaf(ax, W2s[30 * 32 + j0 + 0], fmaf(ay, W2s[31 * 32 + j0 + 0], b2s[j0 + 0]));
            float c1 = fmaf(ax, W2s[30 * 32 + j0 + 1], fmaf(ay, W2s[31 * 32 + j0 + 1], b2s[j0 + 1]));
            float c2 = fmaf(ax, W2s[30 * 32 + j0 + 2], fmaf(ay, W2s[31 * 32 + j0 + 2], b2s[j0 + 2]));
            float c3 = fmaf(ax, W2s[30 * 32 + j0 + 3], fmaf(ay, W2s[31 * 32 + j0 + 3], b2s[j0 + 3]));
#pragma unroll
            for (int k = 0; k < 30; k++) {
                float hk = hsh[grp * 33 + k];  // group-uniform: broadcast
                c0 = fmaf(hk, W2s[k * 32 + j0 + 0], c0);
                c1 = fmaf(hk, W2s[k * 32 + j0 + 1], c1);
                c2 = fmaf(hk, W2s[k * 32 + j0 + 2], c2);
                c3 = fmaf(hk, W2s[k * 32 + j0 + 3], c3);
            }
            // pad dims (j=30,31): W2/b2 zero -> c=0 -> relu 0 -> no contrib
            float s3 = fmaf(fmaxf(c0, 0.f), W3s[j0 + 0], 0.f);
            s3 = fmaf(fmaxf(c1, 0.f), W3s[j0 + 1], s3);
            s3 = fmaf(fmaxf(c2, 0.f), W3s[j0 + 2], s3);
            s3 = fmaf(fmaxf(c3, 0.f), W3s[j0 + 3], s3);
            s3 += __shfl_xor(s3, 1, 8);
            s3 += __shfl_xor(s3, 2, 8);
            s3 += __shfl_xor(s3, 4, 8);
            if (l == 0) {
                s3 = fmaf(xg.x, W3s[30], s3);
                s3 = fmaf(xg.y, W3s[31], s3);
                p3[g] = s3 * rr;
            }
        }
    }
}

// out_v = dinv_v * (p3_v + sum p3_u) + b3.
// 8-lane group per node (R22 mechanism). Lane l strides the csr segment
// (coalesced 32B/group index loads; p3 gathers spread across lanes;
// ~deg/8 iterations/lane); 3x shfl_xor width-8 reduce; lane 0 adds the
// self term and writes out.
__global__ void k_agg1(const float* p3, const int2* iptr2, const int* csr,
                       const float* dinv, const float* b3, float* out, int n) {
    int t = threadIdx.x;
    int g = blockIdx.x * 32 + (t >> 3);
    int l = t & 7;
    if (g >= n) return;
    int2 se = iptr2[g];
    int s = se.x, e = se.y;
    float acc = 0.f;
    for (int i = s + l; i < e; i += 8)
        acc += p3[csr[i]];
    acc += __shfl_xor(acc, 1, 8);
    acc += __shfl_xor(acc, 2, 8);
    acc += __shfl_xor(acc, 4, 8);
    if (l == 0)
        out[g] = fmaf(acc + p3[g], dinv[g], b3[0]);
}

extern "C" void kernel_launch(void* const* d_in, const int* in_sizes, int n_in,
                              void* d_out, int out_size, void* d_ws, size_t ws_size,
                              hipStream_t stream) {
    const float* x  = (const float*)d_in[0];
    const void*  ei = d_in[1];
    const float* W1 = (const float*)d_in[2];
    const float* b1 = (const float*)d_in[3];
    const float* W2 = (const float*)d_in[4];
    const float* b2 = (const float*)d_in[5];
    const float* W3 = (const float*)d_in[6];
    const float* b3 = (const float*)d_in[7];
    float* out = (float*)d_out;
    const int n = in_sizes[0] / 2;
    const long long E = in_sizes[1] / 2;
    const int B = (n + 511) / 512;  // dst buckets of 512 nodes (<=512 buckets)

    char* w = (char*)d_ws;
    auto alloc = [&](size_t b) { void* p = (void*)w; w += (b + 255) & ~(size_t)255; return p; };
    int*            gcnt   = (int*)alloc(512 * 4);
    unsigned*       binned = (unsigned*)alloc((size_t)B * CAP * 4);
    int*            csr    = (int*)alloc((size_t)B * CAP * 4);
    int2*           iptr2  = (int2*)alloc((size_t)n * 8);
    float*          dinv   = (float*)alloc((size_t)n * 4);
    float2*         p1     = (float2*)alloc((size_t)n * 8);
    float4*         t4     = (float4*)alloc((size_t)n * 16);
    float*          p3     = (float*)alloc((size_t)n * 4);

    int nbin = (int)((E + CHUNK - 1) / CHUNK);
    int ngrp = (n + 31) / 32;
    int ngrp4 = (n + 127) / 128;

    hipMemsetAsync(gcnt, 0, 512 * 4, stream);
    k_bin<<<nbin, 512, 0, stream>>>(ei, E, gcnt, binned, B);
    k_bucket_ptr<<<B, 1024, 0, stream>>>(binned, gcnt, x, iptr2, dinv, p1, n);
    k_csr_agg<<<B, 1024, 0, stream>>>(binned, gcnt, iptr2, dinv, p1, csr, t4, n);
    k_agg30_l2<<<ngrp4, 256, 0, stream>>>(t4, iptr2, csr, W1, b1, x,
                                          W2, W3, b2, p3, n);
    k_agg1<<<ngrp, 256, 0, stream>>>(p3, iptr2, csr, dinv, b3, out, n);
}

// Round 19
// 190.098 us; speedup vs baseline: 1.0099x; 1.0099x over previous
//
#include <hip/hip_runtime.h>
#include <stdint.h>

// 3-layer GCN, gather-only aggregation off a per-node CSR.
// R34 = R32 (best, 187.4us; R33's 4-tile loop REVERTED -- its 3 extra
// block-wide barriers coupled all waves to the slowest gather chain,
// occupancy 67->43%, +5.9us) + ONE isolated change in k_agg30_l2:
// BARRIER-FREE PHASE 2. hsh is deleted; lane l already holds its 4 h-dims
// in registers, so phase 2 broadcasts them around the 8-lane group (8
// rounds x 4 width-8 shfl + 16 fma, k=0..31; k=30,31 are h-pads=0 so their
// products with the real W2 skip rows vanish). The single __syncthreads
// (W2s staging guard) moves BEFORE the gather loop -- after it every wave
// runs gather->phase2 fully independently: no max-of-32-nodes coupling,
// phase-2 VALU overlaps other waves' memory stalls.
//  k_bin: CHUNK 6400, single-pass (edges packed in registers), pairs loads.
//  k_bucket_ptr: count + scan -> iptr2, dinv, p1.
//  k_csr_agg: LDS stage + coalesced csr copy-out + per-node dim-2 agg -> t4.
//  k_agg30_l2: fused RECOMPUTE aggregation + layer-2 matmul, shfl phase 2.
//  k_agg1: 8-lane-group gather (R32), shfl_xor reduce.
// Packed edge = (src<<9)|(dst&511), src < 2^18.

#define CAP 9216    // bucket region capacity; mean 8184, sigma 90 -> +11 sigma
#define CHUNK 6400  // edges per k_bin block

__device__ __forceinline__ unsigned short f2bf(float f) {  // RNE, no NaN inputs
    unsigned u = __float_as_uint(f);
    unsigned r = ((u >> 16) & 1u) + 0x7FFFu;
    return (unsigned short)((u + r) >> 16);
}
__device__ __forceinline__ float bf2f(unsigned short h) {
    return __uint_as_float((unsigned)h << 16);
}

// Per-block int64-vs-int32 detect: int64 edge values < 2^18 => all high
// words zero; int32 data at those offsets is src values, ~surely nonzero.
__device__ __forceinline__ int detect64(const unsigned* ei, int* s_nz, int t) {
    unsigned v = ei[2 * (t & 255) + 1];
    if (v != 0) atomicAdd(s_nz, 1);
    __syncthreads();
    return (*s_nz == 0);
}

// Fused binning with local counting sort and coalesced copy-out. 512 thr.
// Edge list read ONCE (pairs via vector loads); packed edges + bucket ids
// held in statically-indexed registers across the scan.
__global__ __launch_bounds__(512) void k_bin(const void* ei, long long E,
                                             int* gcnt, unsigned* binned, int B) {
    __shared__ int cursor[512];
    __shared__ int delta[512];
    __shared__ int wsum[8];
    __shared__ int s_total;
    __shared__ unsigned sv[CHUNK];
    __shared__ unsigned short sb[CHUNK];
    __shared__ int s_nz;
    int t = threadIdx.x, blk = blockIdx.x;
    if (t == 0) s_nz = 0;
    cursor[t] = 0;
    __syncthreads();
    int f = detect64((const unsigned*)ei, &s_nz, t);
    long long s = (long long)blk * CHUNK, e = min(E, s + CHUNK);
    // ---- single global read: pack edges into register slots ----
    unsigned pv[14];
    unsigned short pbk[14];
    if (f) {
        const long long* p = (const long long*)ei;
#pragma unroll
        for (int k = 0; k < 7; k++) {
            long long i = s + 2 * t + (long long)k * 1024;
            if (i + 1 < e) {
                longlong2 sp = *(const longlong2*)(p + i);
                longlong2 dp = *(const longlong2*)(p + E + i);
                pv[2 * k] = ((unsigned)(int)sp.x << 9) | (unsigned)((int)dp.x & 511);
                pbk[2 * k] = (unsigned short)(((int)dp.x) >> 9);
                pv[2 * k + 1] = ((unsigned)(int)sp.y << 9) | (unsigned)((int)dp.y & 511);
                pbk[2 * k + 1] = (unsigned short)(((int)dp.y) >> 9);
            } else if (i < e) {
                int sval = (int)p[i], dv = (int)p[E + i];
                pv[2 * k] = ((unsigned)sval << 9) | (unsigned)(dv & 511);
                pbk[2 * k] = (unsigned short)(dv >> 9);
            }
        }
    } else {
        const int* p = (const int*)ei;
#pragma unroll
        for (int k = 0; k < 7; k++) {
            long long i = s + 2 * t + (long long)k * 1024;
            if (i + 1 < e) {
                int2 sp = *(const int2*)(p + i);
                int2 dp = *(const int2*)(p + E + i);
                pv[2 * k] = ((unsigned)sp.x << 9) | (unsigned)(dp.x & 511);
                pbk[2 * k] = (unsigned short)(dp.x >> 9);
                pv[2 * k + 1] = ((unsigned)sp.y << 9) | (unsigned)(dp.y & 511);
                pbk[2 * k + 1] = (unsigned short)(dp.y >> 9);
            } else if (i < e) {
                int sval = p[i], dv = p[E + i];
                pv[2 * k] = ((unsigned)sval << 9) | (unsigned)(dv & 511);
                pbk[2 * k] = (unsigned short)(dv >> 9);
            }
        }
    }
    // ---- histogram from registers ----
#pragma unroll
    for (int k = 0; k < 14; k++) {
        long long i = s + 2 * t + (long long)(k >> 1) * 1024 + (k & 1);
        if (i < e) atomicAdd(&cursor[pbk[k]], 1);
    }
    __syncthreads();
    // exclusive scan over 512 counts: wave shuffle scan + cross-wave offsets
    int c = cursor[t];
    int lane = t & 63, wid = t >> 6;
    int inc = c;
#pragma unroll
    for (int off = 1; off < 64; off <<= 1) {
        int up = __shfl_up(inc, off, 64);
        if (lane >= off) inc += up;
    }
    if (lane == 63) wsum[wid] = inc;
    __syncthreads();
    int base = 0;
    for (int k = 0; k < wid; k++) base += wsum[k];
    int ex = base + inc - c;
    if (t == 511) s_total = ex + c;
    int claim = c ? atomicAdd(&gcnt[t], c) : 0;
    delta[t] = t * CAP + claim - ex;
    cursor[t] = ex;
    __syncthreads();
    // ---- scatter into LDS from registers ----
#pragma unroll
    for (int k = 0; k < 14; k++) {
        long long i = s + 2 * t + (long long)(k >> 1) * 1024 + (k & 1);
        if (i < e) {
            int pos = atomicAdd(&cursor[pbk[k]], 1);
            sv[pos] = pv[k];
            sb[pos] = pbk[k];
        }
    }
    __syncthreads();
    // linear copy-out (consecutive threads -> consecutive addresses)
    int total = s_total;
    for (int i = t; i < total; i += 512)
        binned[delta[sb[i]] + i] = sv[i];
}

// Per-bucket count + scan only: iptr2, dinv, p1 = x*dinv. 1024 threads.
// (Scatter moved to k_csr_agg, which needs p1 globally complete.)
__global__ __launch_bounds__(1024) void k_bucket_ptr(
        const unsigned* binned, const int* gcnt, const float* x, int2* iptr2,
        float* dinv, float2* p1, int n) {
    __shared__ int cur[512];
    __shared__ int wsum[16];
    int t = threadIdx.x, b = blockIdx.x;
    if (t < 512) cur[t] = 0;
    __syncthreads();
    int cnt = gcnt[b];
    const unsigned* bp = binned + (size_t)b * CAP;
    for (int i = t; i < cnt; i += 1024)
        atomicAdd(&cur[bp[i] & 511u], 1);
    __syncthreads();
    int c = (t < 512) ? cur[t] : 0;
    int lane = t & 63, wid = t >> 6;
    int inc = c;
#pragma unroll
    for (int off = 1; off < 64; off <<= 1) {
        int up = __shfl_up(inc, off, 64);
        if (lane >= off) inc += up;
    }
    if (lane == 63) wsum[wid] = inc;
    __syncthreads();
    int base = 0;
    for (int k = 0; k < wid; k++) base += wsum[k];
    int ex = base + inc - c;
    int gbase = b * CAP;
    if (t < 512) {
        int node = b * 512 + t;
        if (node < n) {
            iptr2[node] = make_int2(gbase + ex, gbase + ex + c);
            float dg = (float)(c + 1);  // +1 self loop
            float r = rsqrtf(dg);
            r = r * (1.5f - 0.5f * dg * r * r);  // Newton refine
            dinv[node] = r;
            p1[node] = make_float2(x[2 * node] * r, x[2 * node + 1] * r);
        }
    }
}

// Phase A: scatter src ids into LDS stage (cursors seeded from iptr2),
// linear coalesced copy-out to csr. Phase B: threads t<512 walk their own
// node's staged segment, gather p1[src] (independent pipelined loads, no
// value atomics), finalize t4 = ((p1_self+agg)*r, r).
__global__ __launch_bounds__(1024) void k_csr_agg(
        const unsigned* binned, const int* gcnt, const int2* iptr2,
        const float* dinv, const float2* p1, int* csr, float4* t4, int n) {
    __shared__ int cur[512];
    __shared__ int stage[CAP];
    int t = threadIdx.x, b = blockIdx.x;
    int seg0 = 0, node = b * 512 + t;
    if (t < 512) {
        seg0 = (node < n) ? iptr2[node].x - b * CAP : 0;
        cur[t] = seg0;
    }
    __syncthreads();
    int cnt = gcnt[b];
    const unsigned* bp = binned + (size_t)b * CAP;
    for (int i = t; i < cnt; i += 1024) {
        unsigned p = bp[i];
        int pos = atomicAdd(&cur[p & 511u], 1);
        stage[pos] = (int)(p >> 9);
    }
    __syncthreads();
    // linear coalesced copy-out
    int gbase = b * CAP;
    for (int i = t; i < cnt; i += 1024)
        csr[gbase + i] = stage[i];
    // phase B: per-node dim-2 aggregation off the staged segment
    if (t < 512 && node < n) {
        int e0 = cur[t];  // segment end after scatter
        float ax = 0.f, ay = 0.f;
        int i = seg0;
        for (; i + 3 < e0; i += 4) {
            int u0 = stage[i], u1 = stage[i + 1];
            int u2 = stage[i + 2], u3 = stage[i + 3];
            float2 q0 = p1[u0], q1 = p1[u1], q2 = p1[u2], q3 = p1[u3];
            ax += (q0.x + q1.x) + (q2.x + q3.x);
            ay += (q0.y + q1.y) + (q2.y + q3.y);
        }
        for (; i < e0; i++) {
            float2 q = p1[stage[i]];
            ax += q.x; ay += q.y;
        }
        float r = dinv[node];
        float2 sp = p1[node];  // self loop
        t4[node] = make_float4((sp.x + ax) * r, (sp.y + ay) * r, r, 0.f);
    }
}

// FUSED dim-30 aggregation + layer 2, BARRIER-FREE PHASE 2.
// W2s/W3s/b2s staged once, ONE barrier (before any latency work). Then each
// 8-lane group runs gather + phase 2 fully independently: lane l holds its
// 4 h-dims in registers; phase 2 broadcasts them with 8 rounds x 4 width-8
// shfl + 16 fma (k=0..31; k=30,31 h-pads=0 so products with the real W2
// skip rows vanish; output pads j=30,31 have zeroed W2 cols/b2 -> 0).
__global__ void k_agg30_l2(const float4* t4, const int2* iptr2, const int* csr,
                           const float* W1, const float* b1, const float* x,
                           const float* W2, const float* W3, const float* b2,
                           float* p3, int n) {
    __shared__ float W2s[32 * 32];   // padded cols (j=30,31 -> 0)
    __shared__ float W3s[32];
    __shared__ float b2s[32];
    int t = threadIdx.x;
    for (int i = t; i < 1024; i += 256) {
        int k = i >> 5, j = i & 31;
        W2s[i] = (j < 30) ? W2[k * 30 + j] : 0.f;
    }
    if (t < 32) {
        W3s[t] = W3[t];
        b2s[t] = (t < 30) ? b2[t] : 0.f;
    }

    int grp = t >> 3, l = t & 7;
    int g = blockIdx.x * 32 + grp;
    bool active = (g < n);

    float w0[4], w1[4], bb[4];
#pragma unroll
    for (int k = 0; k < 4; k++) {
        int j = 4 * l + k;
        bool ok = (j < 30);
        w0[k] = ok ? W1[j] : 0.f;
        w1[k] = ok ? W1[30 + j] : 0.f;
        bb[k] = ok ? b1[j] : 0.f;
    }
    float4 qs = active ? t4[g] : make_float4(0.f, 0.f, 0.f, 0.f);
    float2 xg = active ? *(const float2*)(x + 2 * g) : make_float2(0.f, 0.f);
    // the ONLY barrier: W2s/W3s/b2s visible before use; no latency work yet
    __syncthreads();
    float a0 = fmaxf(fmaf(qs.x, w0[0], fmaf(qs.y, w1[0], bb[0])), 0.f) * qs.z;
    float a1 = fmaxf(fmaf(qs.x, w0[1], fmaf(qs.y, w1[1], bb[1])), 0.f) * qs.z;
    float a2 = fmaxf(fmaf(qs.x, w0[2], fmaf(qs.y, w1[2], bb[2])), 0.f) * qs.z;
    float a3 = fmaxf(fmaf(qs.x, w0[3], fmaf(qs.y, w1[3], bb[3])), 0.f) * qs.z;
    int2 se = active ? iptr2[g] : make_int2(0, 0);
    int s = se.x, e = se.y;
    for (int i = s; i < e; i += 8) {
        int m = e - i;  // valid edges in this chunk (>0)
        int u = (l < m) ? csr[i + l] : 0;
        float4 q = t4[u];
        if (l >= m) { q.x = 0.f; q.y = 0.f; q.z = 0.f; }
#pragma unroll
        for (int k = 0; k < 8; k++) {
            float bx = __shfl(q.x, k, 8);
            float by = __shfl(q.y, k, 8);
            float br = __shfl(q.z, k, 8);
            a0 = fmaf(fmaxf(fmaf(bx, w0[0], fmaf(by, w1[0], bb[0])), 0.f), br, a0);
            a1 = fmaf(fmaxf(fmaf(bx, w0[1], fmaf(by, w1[1], bb[1])), 0.f), br, a1);
            a2 = fmaf(fmaxf(fmaf(bx, w0[2], fmaf(by, w1[2], bb[2])), 0.f), br, a2);
            a3 = fmaf(fmaxf(fmaf(bx, w0[3], fmaf(by, w1[3], bb[3])), 0.f), br, a3);
        }
    }
    // ---- phase 2 (no barrier): shfl-broadcast h around the group ----
    if (active) {
        float rr = qs.z;
        float h0 = a0 * rr, h1 = a1 * rr, h2 = a2 * rr, h3 = a3 * rr;
        int j0 = 4 * l;
        float ax = qs.x, ay = qs.y;
        float c0 = fmaf(ax, W2s[30 * 32 + j0 + 0], fmaf(ay, W2s[31 * 32 + j0 + 0], b2s[j0 + 0]));
        float c1 = fmaf(ax, W2s[30 * 32 + j0 + 1], fmaf(ay, W2s[31 * 32 + j0 + 1], b2s[j0 + 1]));
        float c2 = fmaf(ax, W2s[30 * 32 + j0 + 2], fmaf(ay, W2s[31 * 32 + j0 + 2], b2s[j0 + 2]));
        float c3 = fmaf(ax, W2s[30 * 32 + j0 + 3], fmaf(ay, W2s[31 * 32 + j0 + 3], b2s[j0 + 3]));
#pragma unroll
        for (int kk = 0; kk < 8; kk++) {
            float g0 = __shfl(h0, kk, 8);
            float g1 = __shfl(h1, kk, 8);
            float g2 = __shfl(h2, kk, 8);
            float g3 = __shfl(h3, kk, 8);
            int kb = 4 * kk;
            c0 = fmaf(g0, W2s[(kb + 0) * 32 + j0 + 0], c0);
            c1 = fmaf(g0, W2s[(kb + 0) * 32 + j0 + 1], c1);
            c2 = fmaf(g0, W2s[(kb + 0) * 32 + j0 + 2], c2);
            c3 = fmaf(g0, W2s[(kb + 0) * 32 + j0 + 3], c3);
            c0 = fmaf(g1, W2s[(kb + 1) * 32 + j0 + 0], c0);
            c1 = fmaf(g1, W2s[(kb + 1) * 32 + j0 + 1], c1);
            c2 = fmaf(g1, W2s[(kb + 1) * 32 + j0 + 2], c2);
            c3 = fmaf(g1, W2s[(kb + 1) * 32 + j0 + 3], c3);
            c0 = fmaf(g2, W2s[(kb + 2) * 32 + j0 + 0], c0);
            c1 = fmaf(g2, W2s[(kb + 2) * 32 + j0 + 1], c1);
            c2 = fmaf(g2, W2s[(kb + 2) * 32 + j0 + 2], c2);
            c3 = fmaf(g2, W2s[(kb + 2) * 32 + j0 + 3], c3);
            c0 = fmaf(g3, W2s[(kb + 3) * 32 + j0 + 0], c0);
            c1 = fmaf(g3, W2s[(kb + 3) * 32 + j0 + 1], c1);
            c2 = fmaf(g3, W2s[(kb + 3) * 32 + j0 + 2], c2);
            c3 = fmaf(g3, W2s[(kb + 3) * 32 + j0 + 3], c3);
        }
        float s3 = fmaf(fmaxf(c0, 0.f), W3s[j0 + 0], 0.f);
        s3 = fmaf(fmaxf(c1, 0.f), W3s[j0 + 1], s3);
        s3 = fmaf(fmaxf(c2, 0.f), W3s[j0 + 2], s3);
        s3 = fmaf(fmaxf(c3, 0.f), W3s[j0 + 3], s3);
        s3 += __shfl_xor(s3, 1, 8);
        s3 += __shfl_xor(s3, 2, 8);
        s3 += __shfl_xor(s3, 4, 8);
        if (l == 0) {
            s3 = fmaf(xg.x, W3s[30], s3);
            s3 = fmaf(xg.y, W3s[31], s3);
            p3[g] = s3 * rr;
        }
    }
}

// out_v = dinv_v * (p3_v + sum p3_u) + b3.
// 8-lane group per node (R22 mechanism). Lane l strides the csr segment
// (coalesced 32B/group index loads; p3 gathers spread across lanes;
// ~deg/8 iterations/lane); 3x shfl_xor width-8 reduce; lane 0 adds the
// self term and writes out.
__global__ void k_agg1(const float* p3, const int2* iptr2, const int* csr,
                       const float* dinv, const float* b3, float* out, int n) {
    int t = threadIdx.x;
    int g = blockIdx.x * 32 + (t >> 3);
    int l = t & 7;
    if (g >= n) return;
    int2 se = iptr2[g];
    int s = se.x, e = se.y;
    float acc = 0.f;
    for (int i = s + l; i < e; i += 8)
        acc += p3[csr[i]];
    acc += __shfl_xor(acc, 1, 8);
    acc += __shfl_xor(acc, 2, 8);
    acc += __shfl_xor(acc, 4, 8);
    if (l == 0)
        out[g] = fmaf(acc + p3[g], dinv[g], b3[0]);
}

extern "C" void kernel_launch(void* const* d_in, const int* in_sizes, int n_in,
                              void* d_out, int out_size, void* d_ws, size_t ws_size,
                              hipStream_t stream) {
    const float* x  = (const float*)d_in[0];
    const void*  ei = d_in[1];
    const float* W1 = (const float*)d_in[2];
    const float* b1 = (const float*)d_in[3];
    const float* W2 = (const float*)d_in[4];
    const float* b2 = (const float*)d_in[5];
    const float* W3 = (const float*)d_in[6];
    const float* b3 = (const float*)d_in[7];
    float* out = (float*)d_out;
    const int n = in_sizes[0] / 2;
    const long long E = in_sizes[1] / 2;
    const int B = (n + 511) / 512;  // dst buckets of 512 nodes (<=512 buckets)

    char* w = (char*)d_ws;
    auto alloc = [&](size_t b) { void* p = (void*)w; w += (b + 255) & ~(size_t)255; return p; };
    int*            gcnt   = (int*)alloc(512 * 4);
    unsigned*       binned = (unsigned*)alloc((size_t)B * CAP * 4);
    int*            csr    = (int*)alloc((size_t)B * CAP * 4);
    int2*           iptr2  = (int2*)alloc((size_t)n * 8);
    float*          dinv   = (float*)alloc((size_t)n * 4);
    float2*         p1     = (float2*)alloc((size_t)n * 8);
    float4*         t4     = (float4*)alloc((size_t)n * 16);
    float*          p3     = (float*)alloc((size_t)n * 4);

    int nbin = (int)((E + CHUNK - 1) / CHUNK);
    int ngrp = (n + 31) / 32;

    hipMemsetAsync(gcnt, 0, 512 * 4, stream);
    k_bin<<<nbin, 512, 0, stream>>>(ei, E, gcnt, binned, B);
    k_bucket_ptr<<<B, 1024, 0, stream>>>(binned, gcnt, x, iptr2, dinv, p1, n);
    k_csr_agg<<<B, 1024, 0, stream>>>(binned, gcnt, iptr2, dinv, p1, csr, t4, n);
    k_agg30_l2<<<ngrp, 256, 0, stream>>>(t4, iptr2, csr, W1, b1, x,
                                         W2, W3, b2, p3, n);
    k_agg1<<<ngrp, 256, 0, stream>>>(p3, iptr2, csr, dinv, b3, out, n);
}

// Round 20
// 186.790 us; speedup vs baseline: 1.0278x; 1.0177x over previous
//
#include <hip/hip_runtime.h>
#include <stdint.h>

// 3-layer GCN, gather-only aggregation off a per-node CSR.
// R35 = R32 RESTORED EXACTLY (verified best: 187.4us, absmax 2.44e-4).
// R33 (4-tile amortization: +5.9us, barrier coupling) and R34 (shfl phase 2:
// +5.4us, DS-pipe serialization) both regressed k_agg30_l2 from its 45.0us
// measured optimum -- six mechanisms tried on that kernel, all <=0; its
// single-barrier hsh form is the bracket-confirmed optimum.
//  k_bin: CHUNK 6400, single-pass (edges packed in registers), pairs loads.
//  k_bucket_ptr: count + scan -> iptr2, dinv, p1.
//  k_csr_agg: LDS stage + coalesced csr copy-out + per-node dim-2 agg -> t4.
//  k_agg30_l2: fused RECOMPUTE aggregation + layer-2 matmul, all-lane
//  phase 2 (R26 loop form + xg prefetch; measured 45.0us @ 67% occ).
//  k_agg1: 8-lane-group gather (R32 win, -3.5us), shfl_xor reduce.
// Packed edge = (src<<9)|(dst&511), src < 2^18.

#define CAP 9216    // bucket region capacity; mean 8184, sigma 90 -> +11 sigma
#define CHUNK 6400  // edges per k_bin block

__device__ __forceinline__ unsigned short f2bf(float f) {  // RNE, no NaN inputs
    unsigned u = __float_as_uint(f);
    unsigned r = ((u >> 16) & 1u) + 0x7FFFu;
    return (unsigned short)((u + r) >> 16);
}
__device__ __forceinline__ float bf2f(unsigned short h) {
    return __uint_as_float((unsigned)h << 16);
}

// Per-block int64-vs-int32 detect: int64 edge values < 2^18 => all high
// words zero; int32 data at those offsets is src values, ~surely nonzero.
__device__ __forceinline__ int detect64(const unsigned* ei, int* s_nz, int t) {
    unsigned v = ei[2 * (t & 255) + 1];
    if (v != 0) atomicAdd(s_nz, 1);
    __syncthreads();
    return (*s_nz == 0);
}

// Fused binning with local counting sort and coalesced copy-out. 512 thr.
// Edge list read ONCE (pairs via vector loads); packed edges + bucket ids
// held in statically-indexed registers across the scan.
__global__ __launch_bounds__(512) void k_bin(const void* ei, long long E,
                                             int* gcnt, unsigned* binned, int B) {
    __shared__ int cursor[512];
    __shared__ int delta[512];
    __shared__ int wsum[8];
    __shared__ int s_total;
    __shared__ unsigned sv[CHUNK];
    __shared__ unsigned short sb[CHUNK];
    __shared__ int s_nz;
    int t = threadIdx.x, blk = blockIdx.x;
    if (t == 0) s_nz = 0;
    cursor[t] = 0;
    __syncthreads();
    int f = detect64((const unsigned*)ei, &s_nz, t);
    long long s = (long long)blk * CHUNK, e = min(E, s + CHUNK);
    // ---- single global read: pack edges into register slots ----
    unsigned pv[14];
    unsigned short pbk[14];
    if (f) {
        const long long* p = (const long long*)ei;
#pragma unroll
        for (int k = 0; k < 7; k++) {
            long long i = s + 2 * t + (long long)k * 1024;
            if (i + 1 < e) {
                longlong2 sp = *(const longlong2*)(p + i);
                longlong2 dp = *(const longlong2*)(p + E + i);
                pv[2 * k] = ((unsigned)(int)sp.x << 9) | (unsigned)((int)dp.x & 511);
                pbk[2 * k] = (unsigned short)(((int)dp.x) >> 9);
                pv[2 * k + 1] = ((unsigned)(int)sp.y << 9) | (unsigned)((int)dp.y & 511);
                pbk[2 * k + 1] = (unsigned short)(((int)dp.y) >> 9);
            } else if (i < e) {
                int sval = (int)p[i], dv = (int)p[E + i];
                pv[2 * k] = ((unsigned)sval << 9) | (unsigned)(dv & 511);
                pbk[2 * k] = (unsigned short)(dv >> 9);
            }
        }
    } else {
        const int* p = (const int*)ei;
#pragma unroll
        for (int k = 0; k < 7; k++) {
            long long i = s + 2 * t + (long long)k * 1024;
            if (i + 1 < e) {
                int2 sp = *(const int2*)(p + i);
                int2 dp = *(const int2*)(p + E + i);
                pv[2 * k] = ((unsigned)sp.x << 9) | (unsigned)(dp.x & 511);
                pbk[2 * k] = (unsigned short)(dp.x >> 9);
                pv[2 * k + 1] = ((unsigned)sp.y << 9) | (unsigned)(dp.y & 511);
                pbk[2 * k + 1] = (unsigned short)(dp.y >> 9);
            } else if (i < e) {
                int sval = p[i], dv = p[E + i];
                pv[2 * k] = ((unsigned)sval << 9) | (unsigned)(dv & 511);
                pbk[2 * k] = (unsigned short)(dv >> 9);
            }
        }
    }
    // ---- histogram from registers ----
#pragma unroll
    for (int k = 0; k < 14; k++) {
        long long i = s + 2 * t + (long long)(k >> 1) * 1024 + (k & 1);
        if (i < e) atomicAdd(&cursor[pbk[k]], 1);
    }
    __syncthreads();
    // exclusive scan over 512 counts: wave shuffle scan + cross-wave offsets
    int c = cursor[t];
    int lane = t & 63, wid = t >> 6;
    int inc = c;
#pragma unroll
    for (int off = 1; off < 64; off <<= 1) {
        int up = __shfl_up(inc, off, 64);
        if (lane >= off) inc += up;
    }
    if (lane == 63) wsum[wid] = inc;
    __syncthreads();
    int base = 0;
    for (int k = 0; k < wid; k++) base += wsum[k];
    int ex = base + inc - c;
    if (t == 511) s_total = ex + c;
    int claim = c ? atomicAdd(&gcnt[t], c) : 0;
    delta[t] = t * CAP + claim - ex;
    cursor[t] = ex;
    __syncthreads();
    // ---- scatter into LDS from registers ----
#pragma unroll
    for (int k = 0; k < 14; k++) {
        long long i = s + 2 * t + (long long)(k >> 1) * 1024 + (k & 1);
        if (i < e) {
            int pos = atomicAdd(&cursor[pbk[k]], 1);
            sv[pos] = pv[k];
            sb[pos] = pbk[k];
        }
    }
    __syncthreads();
    // linear copy-out (consecutive threads -> consecutive addresses)
    int total = s_total;
    for (int i = t; i < total; i += 512)
        binned[delta[sb[i]] + i] = sv[i];
}

// Per-bucket count + scan only: iptr2, dinv, p1 = x*dinv. 1024 threads.
// (Scatter moved to k_csr_agg, which needs p1 globally complete.)
__global__ __launch_bounds__(1024) void k_bucket_ptr(
        const unsigned* binned, const int* gcnt, const float* x, int2* iptr2,
        float* dinv, float2* p1, int n) {
    __shared__ int cur[512];
    __shared__ int wsum[16];
    int t = threadIdx.x, b = blockIdx.x;
    if (t < 512) cur[t] = 0;
    __syncthreads();
    int cnt = gcnt[b];
    const unsigned* bp = binned + (size_t)b * CAP;
    for (int i = t; i < cnt; i += 1024)
        atomicAdd(&cur[bp[i] & 511u], 1);
    __syncthreads();
    int c = (t < 512) ? cur[t] : 0;
    int lane = t & 63, wid = t >> 6;
    int inc = c;
#pragma unroll
    for (int off = 1; off < 64; off <<= 1) {
        int up = __shfl_up(inc, off, 64);
        if (lane >= off) inc += up;
    }
    if (lane == 63) wsum[wid] = inc;
    __syncthreads();
    int base = 0;
    for (int k = 0; k < wid; k++) base += wsum[k];
    int ex = base + inc - c;
    int gbase = b * CAP;
    if (t < 512) {
        int node = b * 512 + t;
        if (node < n) {
            iptr2[node] = make_int2(gbase + ex, gbase + ex + c);
            float dg = (float)(c + 1);  // +1 self loop
            float r = rsqrtf(dg);
            r = r * (1.5f - 0.5f * dg * r * r);  // Newton refine
            dinv[node] = r;
            p1[node] = make_float2(x[2 * node] * r, x[2 * node + 1] * r);
        }
    }
}

// Phase A: scatter src ids into LDS stage (cursors seeded from iptr2),
// linear coalesced copy-out to csr. Phase B: threads t<512 walk their own
// node's staged segment, gather p1[src] (independent pipelined loads, no
// value atomics), finalize t4 = ((p1_self+agg)*r, r).
__global__ __launch_bounds__(1024) void k_csr_agg(
        const unsigned* binned, const int* gcnt, const int2* iptr2,
        const float* dinv, const float2* p1, int* csr, float4* t4, int n) {
    __shared__ int cur[512];
    __shared__ int stage[CAP];
    int t = threadIdx.x, b = blockIdx.x;
    int seg0 = 0, node = b * 512 + t;
    if (t < 512) {
        seg0 = (node < n) ? iptr2[node].x - b * CAP : 0;
        cur[t] = seg0;
    }
    __syncthreads();
    int cnt = gcnt[b];
    const unsigned* bp = binned + (size_t)b * CAP;
    for (int i = t; i < cnt; i += 1024) {
        unsigned p = bp[i];
        int pos = atomicAdd(&cur[p & 511u], 1);
        stage[pos] = (int)(p >> 9);
    }
    __syncthreads();
    // linear coalesced copy-out
    int gbase = b * CAP;
    for (int i = t; i < cnt; i += 1024)
        csr[gbase + i] = stage[i];
    // phase B: per-node dim-2 aggregation off the staged segment
    if (t < 512 && node < n) {
        int e0 = cur[t];  // segment end after scatter
        float ax = 0.f, ay = 0.f;
        int i = seg0;
        for (; i + 3 < e0; i += 4) {
            int u0 = stage[i], u1 = stage[i + 1];
            int u2 = stage[i + 2], u3 = stage[i + 3];
            float2 q0 = p1[u0], q1 = p1[u1], q2 = p1[u2], q3 = p1[u3];
            ax += (q0.x + q1.x) + (q2.x + q3.x);
            ay += (q0.y + q1.y) + (q2.y + q3.y);
        }
        for (; i < e0; i++) {
            float2 q = p1[stage[i]];
            ax += q.x; ay += q.y;
        }
        float r = dinv[node];
        float2 sp = p1[node];  // self loop
        t4[node] = make_float4((sp.x + ax) * r, (sp.y + ay) * r, r, 0.f);
    }
}

// FUSED dim-30 aggregation + layer 2 (all-lane phase 2). R26 loop form.
// Phase 1 (all 256 thr, 32 nodes/block, 8 lanes/node): recompute +
// shuffle-broadcast aggregation; deposits the fp32 h-row (incl. final *r)
// into LDS hsh (stride 33).
// Phase 2 (all 256 thr): lane l computes output dims j=4l..4l+3 from hsh
// (broadcast reads) + W2s; relu(acc)@W3 partial tree-reduced over the group
// (3x shfl_xor width 8); lane 0 adds x-skip terms, writes p3 = s3*r.
__global__ void k_agg30_l2(const float4* t4, const int2* iptr2, const int* csr,
                           const float* W1, const float* b1, const float* x,
                           const float* W2, const float* W3, const float* b2,
                           float* p3, int n) {
    __shared__ float hsh[32 * 33];   // fp32 h rows, stride 33 (conflict-free)
    __shared__ float W2s[32 * 32];   // padded rows (j=30,31 -> 0)
    __shared__ float W3s[32];
    __shared__ float b2s[32];
    int t = threadIdx.x;
    for (int i = t; i < 1024; i += 256) {
        int k = i >> 5, j = i & 31;
        W2s[i] = (j < 30) ? W2[k * 30 + j] : 0.f;
    }
    if (t < 32) {
        W3s[t] = W3[t];
        b2s[t] = (t < 30) ? b2[t] : 0.f;
    }

    int grp = t >> 3, l = t & 7;
    int g = blockIdx.x * 32 + grp;
    bool active = (g < n);

    float w0[4], w1[4], bb[4];
#pragma unroll
    for (int k = 0; k < 4; k++) {
        int j = 4 * l + k;
        bool ok = (j < 30);
        w0[k] = ok ? W1[j] : 0.f;
        w1[k] = ok ? W1[30 + j] : 0.f;
        bb[k] = ok ? b1[j] : 0.f;
    }
    float4 qs = active ? t4[g] : make_float4(0.f, 0.f, 0.f, 0.f);
    float2 xg = active ? *(const float2*)(x + 2 * g) : make_float2(0.f, 0.f);
    float a0 = fmaxf(fmaf(qs.x, w0[0], fmaf(qs.y, w1[0], bb[0])), 0.f) * qs.z;
    float a1 = fmaxf(fmaf(qs.x, w0[1], fmaf(qs.y, w1[1], bb[1])), 0.f) * qs.z;
    float a2 = fmaxf(fmaf(qs.x, w0[2], fmaf(qs.y, w1[2], bb[2])), 0.f) * qs.z;
    float a3 = fmaxf(fmaf(qs.x, w0[3], fmaf(qs.y, w1[3], bb[3])), 0.f) * qs.z;
    int2 se = active ? iptr2[g] : make_int2(0, 0);
    int s = se.x, e = se.y;
    for (int i = s; i < e; i += 8) {
        int m = e - i;  // valid edges in this chunk (>0)
        int u = (l < m) ? csr[i + l] : 0;
        float4 q = t4[u];
        if (l >= m) { q.x = 0.f; q.y = 0.f; q.z = 0.f; }
#pragma unroll
        for (int k = 0; k < 8; k++) {
            float bx = __shfl(q.x, k, 8);
            float by = __shfl(q.y, k, 8);
            float br = __shfl(q.z, k, 8);
            a0 = fmaf(fmaxf(fmaf(bx, w0[0], fmaf(by, w1[0], bb[0])), 0.f), br, a0);
            a1 = fmaf(fmaxf(fmaf(bx, w0[1], fmaf(by, w1[1], bb[1])), 0.f), br, a1);
            a2 = fmaf(fmaxf(fmaf(bx, w0[2], fmaf(by, w1[2], bb[2])), 0.f), br, a2);
            a3 = fmaf(fmaxf(fmaf(bx, w0[3], fmaf(by, w1[3], bb[3])), 0.f), br, a3);
        }
    }
    if (active) {
        float r = qs.z;
        int hb = grp * 33 + 4 * l;  // phase-1 writes: 2-way bank alias = free
        hsh[hb + 0] = a0 * r;
        hsh[hb + 1] = a1 * r;
        hsh[hb + 2] = a2 * r;
        hsh[hb + 3] = a3 * r;
    }
    __syncthreads();
    // ---- phase 2: all lanes; lane l owns output dims j=4l..4l+3 ----
    if (active) {
        int j0 = 4 * l;
        float ax = qs.x, ay = qs.y, rr = qs.z;
        float c0 = fmaf(ax, W2s[30 * 32 + j0 + 0], fmaf(ay, W2s[31 * 32 + j0 + 0], b2s[j0 + 0]));
        float c1 = fmaf(ax, W2s[30 * 32 + j0 + 1], fmaf(ay, W2s[31 * 32 + j0 + 1], b2s[j0 + 1]));
        float c2 = fmaf(ax, W2s[30 * 32 + j0 + 2], fmaf(ay, W2s[31 * 32 + j0 + 2], b2s[j0 + 2]));
        float c3 = fmaf(ax, W2s[30 * 32 + j0 + 3], fmaf(ay, W2s[31 * 32 + j0 + 3], b2s[j0 + 3]));
#pragma unroll
        for (int k = 0; k < 30; k++) {
            float hk = hsh[grp * 33 + k];  // same addr across group: broadcast
            c0 = fmaf(hk, W2s[k * 32 + j0 + 0], c0);
            c1 = fmaf(hk, W2s[k * 32 + j0 + 1], c1);
            c2 = fmaf(hk, W2s[k * 32 + j0 + 2], c2);
            c3 = fmaf(hk, W2s[k * 32 + j0 + 3], c3);
        }
        // pad dims (j=30,31): W2/b2 zero -> c=0 -> relu 0 -> no contribution
        float s3 = fmaf(fmaxf(c0, 0.f), W3s[j0 + 0], 0.f);
        s3 = fmaf(fmaxf(c1, 0.f), W3s[j0 + 1], s3);
        s3 = fmaf(fmaxf(c2, 0.f), W3s[j0 + 2], s3);
        s3 = fmaf(fmaxf(c3, 0.f), W3s[j0 + 3], s3);
        s3 += __shfl_xor(s3, 1, 8);
        s3 += __shfl_xor(s3, 2, 8);
        s3 += __shfl_xor(s3, 4, 8);
        if (l == 0) {
            s3 = fmaf(xg.x, W3s[30], s3);
            s3 = fmaf(xg.y, W3s[31], s3);
            p3[g] = s3 * rr;
        }
    }
}

// out_v = dinv_v * (p3_v + sum p3_u) + b3.
// 8-lane group per node (R22 mechanism). Lane l strides the csr segment
// (coalesced 32B/group index loads; p3 gathers spread across lanes;
// ~deg/8 iterations/lane); 3x shfl_xor width-8 reduce; lane 0 adds the
// self term and writes out.
__global__ void k_agg1(const float* p3, const int2* iptr2, const int* csr,
                       const float* dinv, const float* b3, float* out, int n) {
    int t = threadIdx.x;
    int g = blockIdx.x * 32 + (t >> 3);
    int l = t & 7;
    if (g >= n) return;
    int2 se = iptr2[g];
    int s = se.x, e = se.y;
    float acc = 0.f;
    for (int i = s + l; i < e; i += 8)
        acc += p3[csr[i]];
    acc += __shfl_xor(acc, 1, 8);
    acc += __shfl_xor(acc, 2, 8);
    acc += __shfl_xor(acc, 4, 8);
    if (l == 0)
        out[g] = fmaf(acc + p3[g], dinv[g], b3[0]);
}

extern "C" void kernel_launch(void* const* d_in, const int* in_sizes, int n_in,
                              void* d_out, int out_size, void* d_ws, size_t ws_size,
                              hipStream_t stream) {
    const float* x  = (const float*)d_in[0];
    const void*  ei = d_in[1];
    const float* W1 = (const float*)d_in[2];
    const float* b1 = (const float*)d_in[3];
    const float* W2 = (const float*)d_in[4];
    const float* b2 = (const float*)d_in[5];
    const float* W3 = (const float*)d_in[6];
    const float* b3 = (const float*)d_in[7];
    float* out = (float*)d_out;
    const int n = in_sizes[0] / 2;
    const long long E = in_sizes[1] / 2;
    const int B = (n + 511) / 512;  // dst buckets of 512 nodes (<=512 buckets)

    char* w = (char*)d_ws;
    auto alloc = [&](size_t b) { void* p = (void*)w; w += (b + 255) & ~(size_t)255; return p; };
    int*            gcnt   = (int*)alloc(512 * 4);
    unsigned*       binned = (unsigned*)alloc((size_t)B * CAP * 4);
    int*            csr    = (int*)alloc((size_t)B * CAP * 4);
    int2*           iptr2  = (int2*)alloc((size_t)n * 8);
    float*          dinv   = (float*)alloc((size_t)n * 4);
    float2*         p1     = (float2*)alloc((size_t)n * 8);
    float4*         t4     = (float4*)alloc((size_t)n * 16);
    float*          p3     = (float*)alloc((size_t)n * 4);

    int nbin = (int)((E + CHUNK - 1) / CHUNK);
    int ngrp = (n + 31) / 32;

    hipMemsetAsync(gcnt, 0, 512 * 4, stream);
    k_bin<<<nbin, 512, 0, stream>>>(ei, E, gcnt, binned, B);
    k_bucket_ptr<<<B, 1024, 0, stream>>>(binned, gcnt, x, iptr2, dinv, p1, n);
    k_csr_agg<<<B, 1024, 0, stream>>>(binned, gcnt, iptr2, dinv, p1, csr, t4, n);
    k_agg30_l2<<<ngrp, 256, 0, stream>>>(t4, iptr2, csr, W1, b1, x,
                                         W2, W3, b2, p3, n);
    k_agg1<<<ngrp, 256, 0, stream>>>(p3, iptr2, csr, dinv, b3, out, n);
}